// Round 9
// baseline (102.234 us; speedup 1.0000x reference)
//
#include <hip/hip_runtime.h>

// Problem constants (fixed by setup_inputs).
constexpr int L  = 512;   // sequence length
constexpr int CS = 384;   // c_s
constexpr int CH = 32;    // c_h
constexpr int CZ = 128;   // c_z
constexpr float LN_EPS = 1e-5f;

typedef float f4 __attribute__((ext_vector_type(4)));

// ---------------------------------------------------------------------------
// Kernel 1: LayerNorm over c_s + dual projection (w1/b1, w2/b2) + mask.
// ---------------------------------------------------------------------------
__global__ __launch_bounds__(256) void k_ln_proj(
    const float* __restrict__ s, const int* __restrict__ mask,
    const float* __restrict__ ln_scale, const float* __restrict__ ln_bias,
    const float* __restrict__ w1, const float* __restrict__ b1,
    const float* __restrict__ w2, const float* __restrict__ b2,
    float* __restrict__ a, float* __restrict__ b)
{
    __shared__ float sn_lds[4][CS];
    const int wave = threadIdx.x >> 6;
    const int lane = threadIdx.x & 63;
    const int row  = blockIdx.x * 4 + wave;

    const float* srow = s + row * CS;
    float v[6];
    float sum = 0.f, sumsq = 0.f;
#pragma unroll
    for (int q = 0; q < 6; ++q) {
        v[q] = srow[lane + 64 * q];
        sum   += v[q];
        sumsq += v[q] * v[q];
    }
#pragma unroll
    for (int off = 32; off; off >>= 1) {
        sum   += __shfl_xor(sum, off);
        sumsq += __shfl_xor(sumsq, off);
    }
    const float mu   = sum * (1.f / CS);
    const float var  = sumsq * (1.f / CS) - mu * mu;
    const float rstd = rsqrtf(var + LN_EPS);
#pragma unroll
    for (int q = 0; q < 6; ++q) {
        const int k = lane + 64 * q;
        sn_lds[wave][k] = (v[q] - mu) * rstd * ln_scale[k] + ln_bias[k];
    }
    __syncthreads();

    const int c    = lane & 31;
    const int half = lane >> 5;
    const float* W  = half ? w2 : w1;
    const float* Bv = half ? b2 : b1;
    float acc = 0.f;
#pragma unroll 4
    for (int k = 0; k < CS; ++k)
        acc += sn_lds[wave][k] * W[k * CH + c];
    const float m = (float)mask[row];
    const float outv = (acc + Bv[c]) * m;
    (half ? b : a)[row * CH + c] = outv;
}

// ---------------------------------------------------------------------------
// Kernel 2: T[j][c][z] = sum_e b[j][e] * w_out[(c*CH+e)*CZ + z]  (8 MB in ws).
// ---------------------------------------------------------------------------
__global__ __launch_bounds__(512) void k_T(
    const float* __restrict__ b, const float* __restrict__ w_out,
    float* __restrict__ T)
{
    const int czg = blockIdx.x & 7;
    const int jg  = blockIdx.x >> 3;
    const int t   = threadIdx.x;
    const int idx = czg * 512 + t;
    const int c   = idx >> 7;
    const int z   = idx & (CZ - 1);

    float w[CH];
    const float* wp = w_out + (size_t)(c * CH) * CZ + z;
#pragma unroll
    for (int e = 0; e < CH; ++e) w[e] = wp[e * CZ];

    __shared__ float b_lds[64][CH];
    ((float4*)b_lds)[t] = ((const float4*)(b + (size_t)jg * 64 * CH))[t];
    __syncthreads();

    float* Tp = T + (size_t)(jg * 64) * (CH * CZ) + idx;
#pragma unroll 4
    for (int jj = 0; jj < 64; ++jj) {
        float acc = 0.f;
#pragma unroll
        for (int e = 0; e < CH; ++e) acc += b_lds[jj][e] * w[e];
        Tp[(size_t)jj * (CH * CZ)] = acc;
    }
}

// ---------------------------------------------------------------------------
// Kernel 3: z[i,j,:] = a[i,:] @ T[j,:,:] + b_out.
// FULL-OCCUPANCY design (32 waves/CU — Little's law on the L2 store path):
//   lane owns ONE z  -> T column = 32 VGPRs; total ~55 VGPR <= 64
//   (__launch_bounds__(512,8) pins 8 waves/EU = 32 waves/CU).
//   block = 512 thr = 4 j x 128 z; grid = 1024 = 4 blocks/CU
//   (LDS 4x8 KB = 32 KB, 2048 thr/CU = hardware max).
//   PLAIN stores (R2@16w: ~2.6 TB/s vs nt flat ~1.8; BW scaled with waves)
//   + per-step s_barrier (the one bad plain cell, R4, lacked it).
//   a-tile (64 rows) in LDS, rows read as uniform broadcast f4;
//   32 scalar FMAs per output float; 256 B contiguous store per wave-step.
// ---------------------------------------------------------------------------
__global__ __launch_bounds__(512, 8) void k_main(
    const float* __restrict__ a, const float* __restrict__ T,
    const float* __restrict__ b_out, float* __restrict__ out)
{
    __shared__ float a_lds[64][CH];    // 8 KB

    const int bid = blockIdx.x;
    const int j0  = (bid & 127) * 4;   // j-tile of 4
    const int i0  = (bid >> 7) * 64;   // i-tile of 64
    const int t   = threadIdx.x;
    const int jl  = t >> 7;            // 0..3
    const int z   = t & (CZ - 1);
    const int j   = j0 + jl;

    // Stage a-tile: 2048 floats = 512 x float4, perfectly coalesced.
    ((float4*)a_lds)[t] = ((const float4*)(a + (size_t)i0 * CH))[t];

    // T column for this lane: 32 VGPRs, reused 64x.
    float Tc[CH];
    const float* Tj = T + (size_t)j * (CH * CZ) + z;
#pragma unroll
    for (int c = 0; c < CH; ++c)
        Tc[c] = Tj[c * CZ];

    const float bo = b_out[z];
    float* op = out + (size_t)i0 * (L * CZ) + (size_t)j * CZ + z;

    __syncthreads();

#pragma unroll 2
    for (int ii = 0; ii < 64; ++ii) {
        __builtin_amdgcn_s_barrier();   // bound intra-block drift; no vmcnt drain
        const f4* ap = (const f4*)&a_lds[ii][0];
        float acc = bo;
#pragma unroll
        for (int q = 0; q < 8; ++q) {
            const f4 r = ap[q];
            acc += r.x * Tc[4 * q + 0] + r.y * Tc[4 * q + 1]
                 + r.z * Tc[4 * q + 2] + r.w * Tc[4 * q + 3];
        }
        op[(size_t)ii * (L * CZ)] = acc;
    }
}

// ---------------------------------------------------------------------------
extern "C" void kernel_launch(void* const* d_in, const int* in_sizes, int n_in,
                              void* d_out, int out_size, void* d_ws, size_t ws_size,
                              hipStream_t stream) {
    const float* s        = (const float*)d_in[0];
    const int*   mask     = (const int*)d_in[1];
    const float* ln_scale = (const float*)d_in[2];
    const float* ln_bias  = (const float*)d_in[3];
    const float* w1       = (const float*)d_in[4];
    const float* b1       = (const float*)d_in[5];
    const float* w2       = (const float*)d_in[6];
    const float* b2       = (const float*)d_in[7];
    const float* w_out    = (const float*)d_in[8];
    const float* b_out    = (const float*)d_in[9];
    float* out = (float*)d_out;

    // Workspace: a [512*32], b [512*32], T [512*32*128]  (8.125 MB total).
    float* a = (float*)d_ws;
    float* b = a + L * CH;
    float* T = b + L * CH;

    k_ln_proj<<<L / 4, 256, 0, stream>>>(s, mask, ln_scale, ln_bias,
                                         w1, b1, w2, b2, a, b);
    k_T<<<L / 8, 512, 0, stream>>>(b, w_out, T);
    k_main<<<1024, 512, 0, stream>>>(a, T, b_out, out);
}

// Round 10
// 97.531 us; speedup vs baseline: 1.0482x; 1.0482x over previous
//
#include <hip/hip_runtime.h>

// Problem constants (fixed by setup_inputs).
constexpr int L  = 512;   // sequence length
constexpr int CS = 384;   // c_s
constexpr int CH = 32;    // c_h
constexpr int CZ = 128;   // c_z
constexpr float LN_EPS = 1e-5f;

typedef float f4 __attribute__((ext_vector_type(4)));

// ---------------------------------------------------------------------------
// Kernel 1: LayerNorm over c_s + dual projection (w1/b1, w2/b2) + mask.
// ---------------------------------------------------------------------------
__global__ __launch_bounds__(256) void k_ln_proj(
    const float* __restrict__ s, const int* __restrict__ mask,
    const float* __restrict__ ln_scale, const float* __restrict__ ln_bias,
    const float* __restrict__ w1, const float* __restrict__ b1,
    const float* __restrict__ w2, const float* __restrict__ b2,
    float* __restrict__ a, float* __restrict__ b)
{
    __shared__ float sn_lds[4][CS];
    const int wave = threadIdx.x >> 6;
    const int lane = threadIdx.x & 63;
    const int row  = blockIdx.x * 4 + wave;

    const float* srow = s + row * CS;
    float v[6];
    float sum = 0.f, sumsq = 0.f;
#pragma unroll
    for (int q = 0; q < 6; ++q) {
        v[q] = srow[lane + 64 * q];
        sum   += v[q];
        sumsq += v[q] * v[q];
    }
#pragma unroll
    for (int off = 32; off; off >>= 1) {
        sum   += __shfl_xor(sum, off);
        sumsq += __shfl_xor(sumsq, off);
    }
    const float mu   = sum * (1.f / CS);
    const float var  = sumsq * (1.f / CS) - mu * mu;
    const float rstd = rsqrtf(var + LN_EPS);
#pragma unroll
    for (int q = 0; q < 6; ++q) {
        const int k = lane + 64 * q;
        sn_lds[wave][k] = (v[q] - mu) * rstd * ln_scale[k] + ln_bias[k];
    }
    __syncthreads();

    const int c    = lane & 31;
    const int half = lane >> 5;
    const float* W  = half ? w2 : w1;
    const float* Bv = half ? b2 : b1;
    float acc = 0.f;
#pragma unroll 4
    for (int k = 0; k < CS; ++k)
        acc += sn_lds[wave][k] * W[k * CH + c];
    const float m = (float)mask[row];
    const float outv = (acc + Bv[c]) * m;
    (half ? b : a)[row * CH + c] = outv;
}

// ---------------------------------------------------------------------------
// Kernel 2: T[j][c][z] = sum_e b[j][e] * w_out[(c*CH+e)*CZ + z]  (8 MB in ws).
// ---------------------------------------------------------------------------
__global__ __launch_bounds__(512) void k_T(
    const float* __restrict__ b, const float* __restrict__ w_out,
    float* __restrict__ T)
{
    const int czg = blockIdx.x & 7;
    const int jg  = blockIdx.x >> 3;
    const int t   = threadIdx.x;
    const int idx = czg * 512 + t;
    const int c   = idx >> 7;
    const int z   = idx & (CZ - 1);

    float w[CH];
    const float* wp = w_out + (size_t)(c * CH) * CZ + z;
#pragma unroll
    for (int e = 0; e < CH; ++e) w[e] = wp[e * CZ];

    __shared__ float b_lds[64][CH];
    ((float4*)b_lds)[t] = ((const float4*)(b + (size_t)jg * 64 * CH))[t];
    __syncthreads();

    float* Tp = T + (size_t)(jg * 64) * (CH * CZ) + idx;
#pragma unroll 4
    for (int jj = 0; jj < 64; ++jj) {
        float acc = 0.f;
#pragma unroll
        for (int e = 0; e < CH; ++e) acc += b_lds[jj][e] * w[e];
        Tp[(size_t)jj * (CH * CZ)] = acc;
    }
}

// ---------------------------------------------------------------------------
// Kernel 3 (DIAGNOSTIC DUAL-WRITE, otherwise byte-identical to R8):
// z[i,j,:] = a[i,:] @ T[j,:,:] + b_out.
// Every result is stored TWICE: plain f4 to d_out (correctness, the path
// under test, unchanged from R8) and nontemporal f4 to a d_ws mirror
// (known-coarse memory — the 6.6 TB/s fillBuffer targets d_ws, 536 MB = 4x
// out_nbytes; we have NO evidence d_out itself exceeds ~1.8 TB/s).
// Delta vs R8's 88.6 us isolates the coarse-path cost of the identical
// store stream:  small delta  => d_out allocation is the bottleneck;
//                ~+75 us      => store pattern theory revives.
// ---------------------------------------------------------------------------
__global__ __launch_bounds__(512, 1) void k_main(
    const float* __restrict__ a, const float* __restrict__ T,
    const float* __restrict__ b_out, float* __restrict__ out,
    float* __restrict__ ws_mirror)
{
    __shared__ float a_lds[L][CH];     // 64 KB: entire a matrix

    const int bid = blockIdx.x;
    const int g   = bid & 7;           // i-lane group == XCD
    const int j0  = (bid >> 3) * 16;   // j-tile of 16
    const int t   = threadIdx.x;
    const int jj  = t >> 5;            // 0..15 within j-tile
    const int zq  = t & 31;            // z-quad index (z = 4*zq)
    const int j   = j0 + jj;

    // Stage the whole a matrix once (coalesced: 8 float4 per thread).
#pragma unroll
    for (int k = 0; k < 8; ++k)
        ((float4*)a_lds)[t + k * 512] = ((const float4*)a)[t + k * 512];

    // T[j] quad-column for this lane: 128 VGPRs, reused for all 512 i.
    f4 T4[CH];
    const f4* Tj = (const f4*)(T + (size_t)j * (CH * CZ)) + zq;
#pragma unroll
    for (int c = 0; c < CH; ++c)
        T4[c] = Tj[c * (CZ / 4)];

    const f4 bo = ((const f4*)b_out)[zq];

    __syncthreads();

    for (int p = 0; p < 32; ++p) {
        __builtin_amdgcn_s_barrier();   // phase alignment; no vmcnt drain
#pragma unroll
        for (int di = 0; di < 2; ++di) {
            const int i = p * 16 + 2 * g + di;
            const f4* ap = (const f4*)&a_lds[i][0];
            f4 acc = bo;
#pragma unroll
            for (int q = 0; q < 8; ++q) {
                const f4 r = ap[q];
                acc += r.x * T4[4 * q + 0];
                acc += r.y * T4[4 * q + 1];
                acc += r.z * T4[4 * q + 2];
                acc += r.w * T4[4 * q + 3];
            }
            const size_t off = (size_t)i * (L * CZ) + (size_t)j * CZ + 4 * zq;
            *(f4*)(out + off) = acc;                                  // path under test
            __builtin_nontemporal_store(acc, (f4*)(ws_mirror + off)); // coarse mirror
        }
    }
}

// ---------------------------------------------------------------------------
extern "C" void kernel_launch(void* const* d_in, const int* in_sizes, int n_in,
                              void* d_out, int out_size, void* d_ws, size_t ws_size,
                              hipStream_t stream) {
    const float* s        = (const float*)d_in[0];
    const int*   mask     = (const int*)d_in[1];
    const float* ln_scale = (const float*)d_in[2];
    const float* ln_bias  = (const float*)d_in[3];
    const float* w1       = (const float*)d_in[4];
    const float* b1       = (const float*)d_in[5];
    const float* w2       = (const float*)d_in[6];
    const float* b2       = (const float*)d_in[7];
    const float* w_out    = (const float*)d_in[8];
    const float* b_out    = (const float*)d_in[9];
    float* out = (float*)d_out;

    // Workspace layout: a [512*32], b [512*32], T [512*32*128] (8.125 MB),
    // then a 134 MB output mirror (ws_size is ~536 MB per harness poison).
    float* a  = (float*)d_ws;
    float* b  = a + L * CH;
    float* T  = b + L * CH;
    float* wm = T + (size_t)L * CH * CZ;

    k_ln_proj<<<L / 4, 256, 0, stream>>>(s, mask, ln_scale, ln_bias,
                                         w1, b1, w2, b2, a, b);
    k_T<<<L / 8, 512, 0, stream>>>(b, w_out, T);
    k_main<<<256, 512, 0, stream>>>(a, T, b_out, out, wm);
}

// Round 11
// 76.935 us; speedup vs baseline: 1.3288x; 1.2677x over previous
//
#include <hip/hip_runtime.h>

// Problem constants (fixed by setup_inputs).
constexpr int L  = 512;   // sequence length
constexpr int CS = 384;   // c_s
constexpr int CH = 32;    // c_h
constexpr int CZ = 128;   // c_z
constexpr float LN_EPS = 1e-5f;

typedef float f2 __attribute__((ext_vector_type(2)));
typedef float f4 __attribute__((ext_vector_type(4)));

// ---------------------------------------------------------------------------
// Kernel 1 (v2): LayerNorm + dual projection + mask.
// grid = 512 blocks x 64 threads (one wave per row; 2 waves/CU chip-wide
// vs v1's 128 waves on half the CUs -> better load-latency hiding).
// ---------------------------------------------------------------------------
__global__ __launch_bounds__(64) void k_ln_proj(
    const float* __restrict__ s, const int* __restrict__ mask,
    const float* __restrict__ ln_scale, const float* __restrict__ ln_bias,
    const float* __restrict__ w1, const float* __restrict__ b1,
    const float* __restrict__ w2, const float* __restrict__ b2,
    float* __restrict__ a, float* __restrict__ b)
{
    __shared__ float sn_lds[CS];
    const int lane = threadIdx.x;
    const int row  = blockIdx.x;

    const float* srow = s + row * CS;
    float v[6];
    float sum = 0.f, sumsq = 0.f;
#pragma unroll
    for (int q = 0; q < 6; ++q) {
        v[q] = srow[lane + 64 * q];
        sum   += v[q];
        sumsq += v[q] * v[q];
    }
#pragma unroll
    for (int off = 32; off; off >>= 1) {
        sum   += __shfl_xor(sum, off);
        sumsq += __shfl_xor(sumsq, off);
    }
    const float mu   = sum * (1.f / CS);
    const float var  = sumsq * (1.f / CS) - mu * mu;
    const float rstd = rsqrtf(var + LN_EPS);
#pragma unroll
    for (int q = 0; q < 6; ++q) {
        const int k = lane + 64 * q;
        sn_lds[k] = (v[q] - mu) * rstd * ln_scale[k] + ln_bias[k];
    }
    __syncthreads();

    const int c    = lane & 31;
    const int half = lane >> 5;
    const float* W  = half ? w2 : w1;
    const float* Bv = half ? b2 : b1;
    float acc = 0.f;
#pragma unroll 4
    for (int k = 0; k < CS; ++k)
        acc += sn_lds[k] * W[k * CH + c];
    const float m = (float)mask[row];
    const float outv = (acc + Bv[c]) * m;
    (half ? b : a)[row * CH + c] = outv;
}

// ---------------------------------------------------------------------------
// Kernel 2 (v2): T[j][c][z] = sum_e b[j][e] * w_out[(c*CH+e)*CZ + z].
// No LDS, no barrier, no serial broadcast chain (v1 suspect: ~29 us from 64
// blocks + 2048 uniform ds_read + dependent-FMA chains).
// grid = 256 blocks (1/CU); block owns a j-PAIR; thread owns (c, z-octet):
//   - b[j0],b[j1] rows as wave-uniform broadcast loads (64 VGPRs)
//   - 64 independent f4 loads of L2-hot w_out (512 KB, read 1x per block)
//   - 512 independent FMAs, two j accumulators reuse each w load
//   - 2x2 f4 stores, 512 B contiguous per 16-lane group.
// ---------------------------------------------------------------------------
__global__ __launch_bounds__(512) void k_T(
    const float* __restrict__ b, const float* __restrict__ w_out,
    float* __restrict__ T)
{
    const int j0  = blockIdx.x * 2;
    const int t   = threadIdx.x;
    const int c   = t >> 4;            // 0..31
    const int zo  = t & 15;            // z-octet: z = 8*zo .. 8*zo+7

    float bj0[CH], bj1[CH];
#pragma unroll
    for (int e = 0; e < CH; ++e) {
        bj0[e] = b[j0 * CH + e];       // wave-uniform -> broadcast
        bj1[e] = b[(j0 + 1) * CH + e];
    }

    const float* wbase = w_out + (size_t)(c * CH) * CZ + 8 * zo;
    f4 a00 = 0.f, a01 = 0.f, a10 = 0.f, a11 = 0.f;
#pragma unroll
    for (int e = 0; e < CH; ++e) {
        const f4 w0 = *(const f4*)(wbase + e * CZ);
        const f4 w1 = *(const f4*)(wbase + e * CZ + 4);
        a00 += bj0[e] * w0;  a01 += bj0[e] * w1;
        a10 += bj1[e] * w0;  a11 += bj1[e] * w1;
    }

    float* Tp0 = T + (size_t)j0 * (CH * CZ) + c * CZ + 8 * zo;
    *(f4*)(Tp0)     = a00;
    *(f4*)(Tp0 + 4) = a01;
    float* Tp1 = Tp0 + CH * CZ;
    *(f4*)(Tp1)     = a10;
    *(f4*)(Tp1 + 4) = a11;
}

// ---------------------------------------------------------------------------
// Kernel 3: z[i,j,:] = a[i,:] @ T[j,:,:] + b_out.
// BYTE-IDENTICAL to the round-3 (84.3 us) version — the fastest measured
// k_main config: 512 blocks (16 waves/CU), lane owns a z-pair (f2), wave
// owns one j, nt stores, no per-step barrier.
// ---------------------------------------------------------------------------
__global__ __launch_bounds__(512) void k_main(
    const float* __restrict__ a, const float* __restrict__ T,
    const float* __restrict__ b_out, float* __restrict__ out)
{
    __shared__ float a_lds[64][CH];    // 8 KB

    const int bid = blockIdx.x;
    const int j0  = (bid & 63) * 8;
    const int i0  = (bid >> 6) * 64;
    const int t   = threadIdx.x;
    const int wave = t >> 6;
    const int lane = t & 63;
    const int j    = j0 + wave;

    // Stage a-tile: 2048 floats, 512 threads x float4.
    ((float4*)a_lds)[t] = ((const float4*)(a + (size_t)i0 * CH))[t];

    // T[j] column pair for this lane: 64 VGPRs.
    float2 T_reg[CH];
    const float* Tj = T + (size_t)j * (CH * CZ) + 2 * lane;
#pragma unroll
    for (int c = 0; c < CH; ++c)
        T_reg[c] = *(const float2*)(Tj + c * CZ);

    const float2 bo = *(const float2*)&b_out[2 * lane];
    float* outp = out + (size_t)i0 * L * CZ + (size_t)j * CZ + 2 * lane;

    __syncthreads();

#pragma unroll 2
    for (int ii = 0; ii < 64; ++ii) {
        const float4* ap = (const float4*)&a_lds[ii][0];
        float av[CH];
#pragma unroll
        for (int q = 0; q < 8; ++q) {
            const float4 tmp = ap[q];
            av[4 * q + 0] = tmp.x;
            av[4 * q + 1] = tmp.y;
            av[4 * q + 2] = tmp.z;
            av[4 * q + 3] = tmp.w;
        }
        float ax = 0.f, ay = 0.f;
#pragma unroll
        for (int c = 0; c < CH; ++c) {
            ax += av[c] * T_reg[c].x;
            ay += av[c] * T_reg[c].y;
        }
        f2 o;
        o.x = ax + bo.x;
        o.y = ay + bo.y;
        __builtin_nontemporal_store(o, (f2*)(outp + (size_t)ii * L * CZ));
    }
}

// ---------------------------------------------------------------------------
extern "C" void kernel_launch(void* const* d_in, const int* in_sizes, int n_in,
                              void* d_out, int out_size, void* d_ws, size_t ws_size,
                              hipStream_t stream) {
    const float* s        = (const float*)d_in[0];
    const int*   mask     = (const int*)d_in[1];
    const float* ln_scale = (const float*)d_in[2];
    const float* ln_bias  = (const float*)d_in[3];
    const float* w1       = (const float*)d_in[4];
    const float* b1       = (const float*)d_in[5];
    const float* w2       = (const float*)d_in[6];
    const float* b2       = (const float*)d_in[7];
    const float* w_out    = (const float*)d_in[8];
    const float* b_out    = (const float*)d_in[9];
    float* out = (float*)d_out;

    // Workspace: a [512*32], b [512*32], T [512*32*128]  (8.125 MB total).
    float* a = (float*)d_ws;
    float* b = a + L * CH;
    float* T = b + L * CH;

    k_ln_proj<<<L, 64, 0, stream>>>(s, mask, ln_scale, ln_bias,
                                    w1, b1, w2, b2, a, b);
    k_T<<<L / 2, 512, 0, stream>>>(b, w_out, T);
    k_main<<<512, 512, 0, stream>>>(a, T, b_out, out);
}